// Round 1
// baseline (784.566 us; speedup 1.0000x reference)
//
#include <hip/hip_runtime.h>
#include <hip/hip_bf16.h>
#include <cstdint>

// SimplifiedMambaSSM on MI355X (gfx950)
// B=8, T=4096, D_MODEL=1024, D_STATE=16. Rows M = B*T = 32768.
//
// Pipeline:
//  K1 convert : x, W_gate, [W_delta;W_B;W_C] -> bf16 workspace copies
//  K2 gemm    : G = Xb @ Wgb^T   (32768x1024x1024 bf16 MFMA, 128x128 tiles)
//  K3 lngate  : xg = sigmoid(LN(G + b_gate)) * x   (in-place over G, bf16)
//  K4 proj    : [delta|B|C] = xg @ Wcat^T (skinny MFMA); epilogue folds
//               softplus/exp(A_diag)/2*log2e so the scan is exp2-ready
//  K5 scan    : h_t = tanh(A_bar h + B) recurrence, 128 lanes, latency chain
//  K6 out     : y = (C .* h) @ W_out^T + D .* x
//
// Constants
#define M_TOK   32768
#define LNEPS   1e-5f
#define TWO_LOG2E 2.8853900817779268f   // 2/ln(2)

typedef float  f32x4 __attribute__((ext_vector_type(4)));
typedef short  s16x8 __attribute__((ext_vector_type(8)));

__device__ __forceinline__ unsigned short f2b(float v) {
  return __builtin_bit_cast(unsigned short, __float2bfloat16(v));
}
__device__ __forceinline__ float b2f(unsigned short u) {
  return __bfloat162float(__builtin_bit_cast(__hip_bfloat16, u));
}

// async global->LDS, 16B per lane. LDS dest is wave-uniform base + lane*16.
// Address-space casts routed through integers (flat->local truncates to the
// 32-bit LDS offset on gfx9+; flat->global is value-preserving).
__device__ __forceinline__ void async_cp16(const void* g, void* l) {
  using gp = const __attribute__((address_space(1))) char*;
  using lp = __attribute__((address_space(3))) char*;
  __builtin_amdgcn_global_load_lds((gp)(uint64_t)g,
                                   (lp)(uint32_t)(uint64_t)l, 16, 0, 0);
}

// ---------------------------------------------------------------- K1 convert
__global__ __launch_bounds__(256) void k_convert(
    const float* __restrict__ x, const float* __restrict__ wg,
    const float* __restrict__ wd, const float* __restrict__ wb,
    const float* __restrict__ wc,
    unsigned short* __restrict__ Xb, unsigned short* __restrict__ Wgb,
    unsigned short* __restrict__ Wcat) {
  int i = blockIdx.x * 256 + threadIdx.x;   // one float4 per thread
  const float* src;
  unsigned short* dst;
  if (i < 8388608) {                  // x: 33554432 floats
    src = x + (size_t)i * 4; dst = Xb + (size_t)i * 4;
  } else if (i < 8650752) {           // W_gate: 1048576 floats
    int j = i - 8388608;
    src = wg + (size_t)j * 4; dst = Wgb + (size_t)j * 4;
  } else {                            // Wcat = [W_delta; W_B; W_C], 49152 floats
    int j = i - 8650752;
    int e = j * 4;
    if (e < 16384)       src = wd + e;
    else if (e < 32768)  src = wb + (e - 16384);
    else                 src = wc + (e - 32768);
    dst = Wcat + e;
  }
  float4 v = *(const float4*)src;
  ushort4 o;
  o.x = f2b(v.x); o.y = f2b(v.y); o.z = f2b(v.z); o.w = f2b(v.w);
  *(ushort4*)dst = o;
}

// ------------------------------------------------------------- K2 gate GEMM
// G[m][n] = sum_k Xb[m][k] * Wgb[n][k]   (NT, both K-contiguous)
// 128x128 block tile, 4 waves in 2x2, each wave 64x64 = 4x4 MFMA 16x16x32.
__global__ __launch_bounds__(256, 2) void k_gemm_gate(
    const unsigned short* __restrict__ A,   // [32768][1024] bf16
    const unsigned short* __restrict__ Bm,  // [1024][1024] bf16 (W_gate rows)
    unsigned short* __restrict__ C) {       // [32768][1024] bf16
  __shared__ unsigned short As[128 * 32];   // 8 KB
  __shared__ unsigned short Bs[128 * 32];   // 8 KB
  const int tid  = threadIdx.x;
  const int wave = tid >> 6, lane = tid & 63;
  const int wr = wave >> 1, wc = wave & 1;
  const int lrow = lane & 15, lq = lane >> 4;
  const int m0 = blockIdx.x * 128;
  const int n0 = blockIdx.y * 128;
  const int crow  = tid >> 2;               // staging chunk row (rep 0)
  const int ccol  = (tid & 3) * 8;          // staging chunk col (elems)

  f32x4 acc[4][4];
#pragma unroll
  for (int i = 0; i < 4; i++)
#pragma unroll
    for (int j = 0; j < 4; j++) acc[i][j] = (f32x4){0.f, 0.f, 0.f, 0.f};

  for (int k0 = 0; k0 < 1024; k0 += 32) {
    // stage 8KB A + 8KB B; chunk c lands at LDS byte c*16; wave w covers
    // chunks [rep*256 + w*64, +64) -> uniform base (rep*256 + w*64)*16B.
    async_cp16(A + (size_t)(m0 + crow) * 1024 + k0 + ccol,
               (void*)(As + (wave * 64) * 8));
    async_cp16(A + (size_t)(m0 + crow + 64) * 1024 + k0 + ccol,
               (void*)(As + (256 + wave * 64) * 8));
    async_cp16(Bm + (size_t)(n0 + crow) * 1024 + k0 + ccol,
               (void*)(Bs + (wave * 64) * 8));
    async_cp16(Bm + (size_t)(n0 + crow + 64) * 1024 + k0 + ccol,
               (void*)(Bs + (256 + wave * 64) * 8));
    __syncthreads();   // drains vmcnt (global_load_lds) before LDS reads

    s16x8 af[4], bfr[4];
#pragma unroll
    for (int i = 0; i < 4; i++)
      af[i] = *(const s16x8*)(As + (wr * 64 + i * 16 + lrow) * 32 + lq * 8);
#pragma unroll
    for (int j = 0; j < 4; j++)
      bfr[j] = *(const s16x8*)(Bs + (wc * 64 + j * 16 + lrow) * 32 + lq * 8);
#pragma unroll
    for (int i = 0; i < 4; i++)
#pragma unroll
      for (int j = 0; j < 4; j++)
        acc[i][j] = __builtin_amdgcn_mfma_f32_16x16x32_bf16(
            af[i], bfr[j], acc[i][j], 0, 0, 0);
    __syncthreads();
  }

  // C/D layout: col = lane&15, row = (lane>>4)*4 + reg
#pragma unroll
  for (int i = 0; i < 4; i++)
#pragma unroll
    for (int j = 0; j < 4; j++)
#pragma unroll
      for (int r = 0; r < 4; r++) {
        int row = m0 + wr * 64 + i * 16 + lq * 4 + r;
        int col = n0 + wc * 64 + j * 16 + lrow;
        C[(size_t)row * 1024 + col] = f2b(acc[i][j][r]);
      }
}

// -------------------------------------------------------------- K3 LN+gate
// One row per block. xg = sigmoid(LN(G+b_gate)*lnw+lnb) * x, written in place
// over G (each thread touches only its own 4 elements -> no hazard).
__global__ __launch_bounds__(256) void k_lngate(
    const unsigned short* Gin, const float* __restrict__ x,
    const float* __restrict__ bg, const float* __restrict__ lnw,
    const float* __restrict__ lnb, unsigned short* XG) {
  __shared__ float red[8];
  const int t = threadIdx.x;
  const size_t r = blockIdx.x;
  const int e = t * 4;

  ushort4 g4 = *(const ushort4*)(Gin + r * 1024 + e);
  float4 bg4 = *(const float4*)(bg + e);
  float v0 = b2f(g4.x) + bg4.x;
  float v1 = b2f(g4.y) + bg4.y;
  float v2 = b2f(g4.z) + bg4.z;
  float v3 = b2f(g4.w) + bg4.w;

  float s  = v0 + v1 + v2 + v3;
  float ss = v0 * v0 + v1 * v1 + v2 * v2 + v3 * v3;
#pragma unroll
  for (int off = 32; off >= 1; off >>= 1) {
    s  += __shfl_xor(s, off, 64);
    ss += __shfl_xor(ss, off, 64);
  }
  if ((t & 63) == 0) { red[t >> 6] = s; red[4 + (t >> 6)] = ss; }
  __syncthreads();
  float tot = red[0] + red[1] + red[2] + red[3];
  float tss = red[4] + red[5] + red[6] + red[7];
  float mu  = tot * (1.0f / 1024.0f);
  float var = tss * (1.0f / 1024.0f) - mu * mu;
  float rs  = rsqrtf(var + LNEPS);

  float4 xv = *(const float4*)(x + r * 1024 + e);
  float4 w4 = *(const float4*)(lnw + e);
  float4 b4 = *(const float4*)(lnb + e);
  float u0 = (v0 - mu) * rs * w4.x + b4.x;
  float u1 = (v1 - mu) * rs * w4.y + b4.y;
  float u2 = (v2 - mu) * rs * w4.z + b4.z;
  float u3 = (v3 - mu) * rs * w4.w + b4.w;
  float g0 = 1.0f / (1.0f + __expf(-u0));
  float g1 = 1.0f / (1.0f + __expf(-u1));
  float g2 = 1.0f / (1.0f + __expf(-u2));
  float g3 = 1.0f / (1.0f + __expf(-u3));
  ushort4 o;
  o.x = f2b(g0 * xv.x); o.y = f2b(g1 * xv.y);
  o.z = f2b(g2 * xv.z); o.w = f2b(g3 * xv.w);
  *(ushort4*)(XG + r * 1024 + e) = o;
}

// ------------------------------------------------------------ K4 projection
// [delta|B|C](r, 0..47) = xg(r,:) @ Wcat^T. 64 rows/block, wave w -> rows
// w*16..+15, 3 MFMA tiles across N=48. Epilogue folds softplus, exp(A_diag*),
// and the 2*log2e scan scaling.
__global__ __launch_bounds__(256) void k_proj(
    const unsigned short* __restrict__ XG, const unsigned short* __restrict__ Wcat,
    const float* __restrict__ A_diag,
    float* __restrict__ A2, float* __restrict__ B2, float* __restrict__ Ct) {
  __shared__ unsigned short As[64 * 32];   // 4 KB
  __shared__ unsigned short Bs[48 * 32];   // 3 KB
  const int tid  = threadIdx.x;
  const int wave = tid >> 6, lane = tid & 63;
  const int lrow = lane & 15, lq = lane >> 4;
  const int r0 = blockIdx.x * 64;
  const int crow = tid >> 2, ccol = (tid & 3) * 8;

  f32x4 acc[3];
#pragma unroll
  for (int j = 0; j < 3; j++) acc[j] = (f32x4){0.f, 0.f, 0.f, 0.f};

  for (int k0 = 0; k0 < 1024; k0 += 32) {
    uint4 av = *(const uint4*)(XG + (size_t)(r0 + crow) * 1024 + k0 + ccol);
    uint4 bv;
    if (tid < 192) bv = *(const uint4*)(Wcat + (size_t)crow * 1024 + k0 + ccol);
    __syncthreads();                       // prev iter done reading LDS
    *(uint4*)(As + crow * 32 + ccol) = av;
    if (tid < 192) *(uint4*)(Bs + crow * 32 + ccol) = bv;
    __syncthreads();
    s16x8 af = *(const s16x8*)(As + (wave * 16 + lrow) * 32 + lq * 8);
#pragma unroll
    for (int j = 0; j < 3; j++) {
      s16x8 bf8 = *(const s16x8*)(Bs + (j * 16 + lrow) * 32 + lq * 8);
      acc[j] = __builtin_amdgcn_mfma_f32_16x16x32_bf16(af, bf8, acc[j], 0, 0, 0);
    }
  }

  float ad = A_diag[lrow];
#pragma unroll
  for (int r = 0; r < 4; r++) {
    int row = r0 + wave * 16 + lq * 4 + r;
    float z  = acc[0][r];
    float sp = fmaxf(z, 0.0f) + log1pf(__expf(-fabsf(z)));  // softplus
    float ab = __expf(sp * ad);                              // A_bar in (0,1]
    A2[(size_t)row * 16 + lrow] = ab * TWO_LOG2E;
    B2[(size_t)row * 16 + lrow] = acc[1][r] * TWO_LOG2E;
    Ct[(size_t)row * 16 + lrow] = acc[2][r];
  }
}

// ------------------------------------------------------------------ K5 scan
// h_t = m*tanh(A_bar h + B) + (1-m) h, 128 chains (b,s). tanh via exp2:
// w = A2*h + B2 (pre-scaled by 2*log2e), tanh = 1 - 2/(exp2(w)+1).
__global__ __launch_bounds__(64) void k_scan(
    const float* __restrict__ A2, const float* __restrict__ B2,
    const float* __restrict__ mask, const float* __restrict__ h0,
    float* __restrict__ hs, float* __restrict__ hfin) {
  const int lane = threadIdx.x;
  const int b = blockIdx.x * 4 + (lane >> 4);
  const int s = lane & 15;
  const size_t base = ((size_t)b * 4096) * 16 + s;
  const float* pm = mask + (size_t)b * 4096;

  float h = h0[b * 16 + s];
  float a2n = A2[base], b2n = B2[base], mn = pm[0];
  for (int t = 0; t < 4096; ++t) {
    float a2 = a2n, b2c = b2n, m = mn;
    int tn = (t + 1 < 4096) ? (t + 1) : 4095;           // branchless prefetch
    a2n = A2[base + (size_t)tn * 16];
    b2n = B2[base + (size_t)tn * 16];
    mn  = pm[tn];
    float onemh = 1.0f - h;                              // off critical path
    float w = fmaf(a2, h, b2c);
    float e = __builtin_amdgcn_exp2f(w);
    float rc = __builtin_amdgcn_rcpf(e + 1.0f);
    float hcmh = fmaf(-2.0f, rc, onemh);                 // tanh(w') - h
    h = fmaf(m, hcmh, h);
    hs[base + (size_t)t * 16] = h;
  }
  hfin[b * 16 + s] = h;
}

// ---------------------------------------------------------------- K6 output
// y[r][d] = sum_s (Ct*hs)[r][s] * W_out[d][s] + D[d]*x[r][d].
// 8 rows/block; W_out chunk (4 d-rows x 16) register-cached per thread.
__global__ __launch_bounds__(256) void k_out(
    const float* __restrict__ Ct, const float* __restrict__ hs,
    const float* __restrict__ Wout, const float* __restrict__ Dd,
    const float* __restrict__ x, float* __restrict__ y) {
  __shared__ float sv[8][16];
  const int t = threadIdx.x;
  const size_t r0 = (size_t)blockIdx.x * 8;
  const int d0 = t * 4;

  float w[4][16];
#pragma unroll
  for (int i = 0; i < 4; i++)
#pragma unroll
    for (int s4 = 0; s4 < 4; s4++)
      *(float4*)&w[i][s4 * 4] = *(const float4*)(Wout + (size_t)(d0 + i) * 16 + s4 * 4);
  float4 D4 = *(const float4*)(Dd + d0);

  if (t < 128) {
    int rr = t >> 4, s = t & 15;
    size_t idx = (r0 + rr) * 16 + s;
    sv[rr][s] = Ct[idx] * hs[idx];
  }
  __syncthreads();

#pragma unroll
  for (int rr = 0; rr < 8; rr++) {
    size_t r = r0 + rr;
    float4 x4 = *(const float4*)(x + r * 1024 + d0);
    float4 o;
    o.x = D4.x * x4.x; o.y = D4.y * x4.y; o.z = D4.z * x4.z; o.w = D4.w * x4.w;
#pragma unroll
    for (int s = 0; s < 16; s++) {
      float svs = sv[rr][s];
      o.x = fmaf(w[0][s], svs, o.x);
      o.y = fmaf(w[1][s], svs, o.y);
      o.z = fmaf(w[2][s], svs, o.z);
      o.w = fmaf(w[3][s], svs, o.w);
    }
    *(float4*)(y + r * 1024 + d0) = o;
  }
}

// ---------------------------------------------------------------- launcher
extern "C" void kernel_launch(void* const* d_in, const int* in_sizes, int n_in,
                              void* d_out, int out_size, void* d_ws, size_t ws_size,
                              hipStream_t stream) {
  const float* x       = (const float*)d_in[0];
  const float* h0      = (const float*)d_in[1];
  const float* mask    = (const float*)d_in[2];
  const float* A_diag  = (const float*)d_in[3];
  const float* W_delta = (const float*)d_in[4];
  const float* W_B     = (const float*)d_in[5];
  const float* W_C     = (const float*)d_in[6];
  const float* W_out   = (const float*)d_in[7];
  const float* Dd      = (const float*)d_in[8];
  const float* W_gate  = (const float*)d_in[9];
  const float* b_gate  = (const float*)d_in[10];
  const float* ln_w    = (const float*)d_in[11];
  const float* ln_b    = (const float*)d_in[12];

  char* ws = (char*)d_ws;
  unsigned short* Xb   = (unsigned short*)(ws);               // 64 MB
  unsigned short* Gb   = (unsigned short*)(ws + 67108864);    // 64 MB (G, then xg in-place)
  unsigned short* Wgb  = (unsigned short*)(ws + 134217728);   // 2 MB
  unsigned short* Wcat = (unsigned short*)(ws + 136314880);   // 96 KB (pad 128K)
  float* A2  = (float*)(ws + 136445952);                      // 2 MB
  float* B2  = (float*)(ws + 138543104);                      // 2 MB
  float* Ctb = (float*)(ws + 140640256);                      // 2 MB
  float* hsb = (float*)(ws + 142737408);                      // 2 MB  (end ~138.1 MB)

  float* y    = (float*)d_out;
  float* hfin = y + 33554432;

  hipLaunchKernelGGL(k_convert, dim3(33840), dim3(256), 0, stream,
                     x, W_gate, W_delta, W_B, W_C, Xb, Wgb, Wcat);
  hipLaunchKernelGGL(k_gemm_gate, dim3(256, 8), dim3(256), 0, stream, Xb, Wgb, Gb);
  hipLaunchKernelGGL(k_lngate, dim3(32768), dim3(256), 0, stream,
                     Gb, x, b_gate, ln_w, ln_b, Gb);
  hipLaunchKernelGGL(k_proj, dim3(512), dim3(256), 0, stream,
                     Gb, Wcat, A_diag, A2, B2, Ctb);
  hipLaunchKernelGGL(k_scan, dim3(2), dim3(64), 0, stream,
                     A2, B2, mask, h0, hsb, hfin);
  hipLaunchKernelGGL(k_out, dim3(4096), dim3(256), 0, stream,
                     Ctb, hsb, W_out, Dd, x, y);
}

// Round 2
// 676.955 us; speedup vs baseline: 1.1590x; 1.1590x over previous
//
#include <hip/hip_runtime.h>
#include <hip/hip_bf16.h>
#include <cstdint>

// SimplifiedMambaSSM on MI355X (gfx950)
// B=8, T=4096, D_MODEL=1024, D_STATE=16. Rows M = B*T = 32768.
//
// Pipeline:
//  K1 convert : x, W_gate, [W_delta;W_B;W_C] -> bf16 workspace copies
//  K2 gemm    : G = Xb @ Wgb^T   (32768x1024x1024 bf16 MFMA, 128x128 tiles)
//  K3 lngate  : xg = sigmoid(LN(G + b_gate)) * x   (in-place over G, bf16)
//  K4 proj    : [delta|B|C] = xg @ Wcat^T (skinny MFMA); epilogue folds
//               softplus/exp(A_diag)/2*log2e, writes interleaved AB pairs
//  K5 scan    : h_t recurrence, 128 chains; 16-step double-buffered register
//               prefetch to hide L2 latency (R1: 1-step prefetch -> 201cyc/step)
//  K6 out     : y = (C .* h) @ W_out^T + D .* x
//
#define M_TOK   32768
#define LNEPS   1e-5f
#define TWO_LOG2E 2.8853900817779268f   // 2/ln(2)
#define CH 16                           // scan prefetch chunk (steps)

typedef float  f32x4 __attribute__((ext_vector_type(4)));
typedef short  s16x8 __attribute__((ext_vector_type(8)));

__device__ __forceinline__ unsigned short f2b(float v) {
  return __builtin_bit_cast(unsigned short, __float2bfloat16(v));
}
__device__ __forceinline__ float b2f(unsigned short u) {
  return __bfloat162float(__builtin_bit_cast(__hip_bfloat16, u));
}

// async global->LDS, 16B per lane. LDS dest is wave-uniform base + lane*16.
__device__ __forceinline__ void async_cp16(const void* g, void* l) {
  using gp = const __attribute__((address_space(1))) char*;
  using lp = __attribute__((address_space(3))) char*;
  __builtin_amdgcn_global_load_lds((gp)(uint64_t)g,
                                   (lp)(uint32_t)(uint64_t)l, 16, 0, 0);
}

// ---------------------------------------------------------------- K1 convert
__global__ __launch_bounds__(256) void k_convert(
    const float* __restrict__ x, const float* __restrict__ wg,
    const float* __restrict__ wd, const float* __restrict__ wb,
    const float* __restrict__ wc,
    unsigned short* __restrict__ Xb, unsigned short* __restrict__ Wgb,
    unsigned short* __restrict__ Wcat) {
  int i = blockIdx.x * 256 + threadIdx.x;   // one float4 per thread
  const float* src;
  unsigned short* dst;
  if (i < 8388608) {                  // x: 33554432 floats
    src = x + (size_t)i * 4; dst = Xb + (size_t)i * 4;
  } else if (i < 8650752) {           // W_gate: 1048576 floats
    int j = i - 8388608;
    src = wg + (size_t)j * 4; dst = Wgb + (size_t)j * 4;
  } else {                            // Wcat = [W_delta; W_B; W_C], 49152 floats
    int j = i - 8650752;
    int e = j * 4;
    if (e < 16384)       src = wd + e;
    else if (e < 32768)  src = wb + (e - 16384);
    else                 src = wc + (e - 32768);
    dst = Wcat + e;
  }
  float4 v = *(const float4*)src;
  ushort4 o;
  o.x = f2b(v.x); o.y = f2b(v.y); o.z = f2b(v.z); o.w = f2b(v.w);
  *(ushort4*)dst = o;
}

// ------------------------------------------------------------- K2 gate GEMM
// G[m][n] = sum_k Xb[m][k] * Wgb[n][k]   (NT, both K-contiguous)
// 128x128 block tile, 4 waves in 2x2, each wave 64x64 = 4x4 MFMA 16x16x32.
__global__ __launch_bounds__(256, 2) void k_gemm_gate(
    const unsigned short* __restrict__ A,   // [32768][1024] bf16
    const unsigned short* __restrict__ Bm,  // [1024][1024] bf16 (W_gate rows)
    unsigned short* __restrict__ C) {       // [32768][1024] bf16
  __shared__ unsigned short As[128 * 32];   // 8 KB
  __shared__ unsigned short Bs[128 * 32];   // 8 KB
  const int tid  = threadIdx.x;
  const int wave = tid >> 6, lane = tid & 63;
  const int wr = wave >> 1, wc = wave & 1;
  const int lrow = lane & 15, lq = lane >> 4;
  const int m0 = blockIdx.x * 128;
  const int n0 = blockIdx.y * 128;
  const int crow  = tid >> 2;               // staging chunk row (rep 0)
  const int ccol  = (tid & 3) * 8;          // staging chunk col (elems)

  f32x4 acc[4][4];
#pragma unroll
  for (int i = 0; i < 4; i++)
#pragma unroll
    for (int j = 0; j < 4; j++) acc[i][j] = (f32x4){0.f, 0.f, 0.f, 0.f};

  for (int k0 = 0; k0 < 1024; k0 += 32) {
    async_cp16(A + (size_t)(m0 + crow) * 1024 + k0 + ccol,
               (void*)(As + (wave * 64) * 8));
    async_cp16(A + (size_t)(m0 + crow + 64) * 1024 + k0 + ccol,
               (void*)(As + (256 + wave * 64) * 8));
    async_cp16(Bm + (size_t)(n0 + crow) * 1024 + k0 + ccol,
               (void*)(Bs + (wave * 64) * 8));
    async_cp16(Bm + (size_t)(n0 + crow + 64) * 1024 + k0 + ccol,
               (void*)(Bs + (256 + wave * 64) * 8));
    __syncthreads();   // drains vmcnt (global_load_lds) before LDS reads

    s16x8 af[4], bfr[4];
#pragma unroll
    for (int i = 0; i < 4; i++)
      af[i] = *(const s16x8*)(As + (wr * 64 + i * 16 + lrow) * 32 + lq * 8);
#pragma unroll
    for (int j = 0; j < 4; j++)
      bfr[j] = *(const s16x8*)(Bs + (wc * 64 + j * 16 + lrow) * 32 + lq * 8);
#pragma unroll
    for (int i = 0; i < 4; i++)
#pragma unroll
      for (int j = 0; j < 4; j++)
        acc[i][j] = __builtin_amdgcn_mfma_f32_16x16x32_bf16(
            af[i], bfr[j], acc[i][j], 0, 0, 0);
    __syncthreads();
  }

  // C/D layout: col = lane&15, row = (lane>>4)*4 + reg
#pragma unroll
  for (int i = 0; i < 4; i++)
#pragma unroll
    for (int j = 0; j < 4; j++)
#pragma unroll
      for (int r = 0; r < 4; r++) {
        int row = m0 + wr * 64 + i * 16 + lq * 4 + r;
        int col = n0 + wc * 64 + j * 16 + lrow;
        C[(size_t)row * 1024 + col] = f2b(acc[i][j][r]);
      }
}

// -------------------------------------------------------------- K3 LN+gate
__global__ __launch_bounds__(256) void k_lngate(
    const unsigned short* Gin, const float* __restrict__ x,
    const float* __restrict__ bg, const float* __restrict__ lnw,
    const float* __restrict__ lnb, unsigned short* XG) {
  __shared__ float red[8];
  const int t = threadIdx.x;
  const size_t r = blockIdx.x;
  const int e = t * 4;

  ushort4 g4 = *(const ushort4*)(Gin + r * 1024 + e);
  float4 bg4 = *(const float4*)(bg + e);
  float v0 = b2f(g4.x) + bg4.x;
  float v1 = b2f(g4.y) + bg4.y;
  float v2 = b2f(g4.z) + bg4.z;
  float v3 = b2f(g4.w) + bg4.w;

  float s  = v0 + v1 + v2 + v3;
  float ss = v0 * v0 + v1 * v1 + v2 * v2 + v3 * v3;
#pragma unroll
  for (int off = 32; off >= 1; off >>= 1) {
    s  += __shfl_xor(s, off, 64);
    ss += __shfl_xor(ss, off, 64);
  }
  if ((t & 63) == 0) { red[t >> 6] = s; red[4 + (t >> 6)] = ss; }
  __syncthreads();
  float tot = red[0] + red[1] + red[2] + red[3];
  float tss = red[4] + red[5] + red[6] + red[7];
  float mu  = tot * (1.0f / 1024.0f);
  float var = tss * (1.0f / 1024.0f) - mu * mu;
  float rs  = rsqrtf(var + LNEPS);

  float4 xv = *(const float4*)(x + r * 1024 + e);
  float4 w4 = *(const float4*)(lnw + e);
  float4 b4 = *(const float4*)(lnb + e);
  float u0 = (v0 - mu) * rs * w4.x + b4.x;
  float u1 = (v1 - mu) * rs * w4.y + b4.y;
  float u2 = (v2 - mu) * rs * w4.z + b4.z;
  float u3 = (v3 - mu) * rs * w4.w + b4.w;
  float g0 = 1.0f / (1.0f + __expf(-u0));
  float g1 = 1.0f / (1.0f + __expf(-u1));
  float g2 = 1.0f / (1.0f + __expf(-u2));
  float g3 = 1.0f / (1.0f + __expf(-u3));
  ushort4 o;
  o.x = f2b(g0 * xv.x); o.y = f2b(g1 * xv.y);
  o.z = f2b(g2 * xv.z); o.w = f2b(g3 * xv.w);
  *(ushort4*)(XG + r * 1024 + e) = o;
}

// ------------------------------------------------------------ K4 projection
// Epilogue writes interleaved AB[row*32 + s*2] = {A_bar*2log2e, B*2log2e}
// so the scan does one dwordx2 load per step.
__global__ __launch_bounds__(256) void k_proj(
    const unsigned short* __restrict__ XG, const unsigned short* __restrict__ Wcat,
    const float* __restrict__ A_diag,
    float* __restrict__ AB, float* __restrict__ Ct) {
  __shared__ unsigned short As[64 * 32];   // 4 KB
  __shared__ unsigned short Bs[48 * 32];   // 3 KB
  const int tid  = threadIdx.x;
  const int wave = tid >> 6, lane = tid & 63;
  const int lrow = lane & 15, lq = lane >> 4;
  const int r0 = blockIdx.x * 64;
  const int crow = tid >> 2, ccol = (tid & 3) * 8;

  f32x4 acc[3];
#pragma unroll
  for (int j = 0; j < 3; j++) acc[j] = (f32x4){0.f, 0.f, 0.f, 0.f};

  for (int k0 = 0; k0 < 1024; k0 += 32) {
    uint4 av = *(const uint4*)(XG + (size_t)(r0 + crow) * 1024 + k0 + ccol);
    uint4 bv;
    if (tid < 192) bv = *(const uint4*)(Wcat + (size_t)crow * 1024 + k0 + ccol);
    __syncthreads();                       // prev iter done reading LDS
    *(uint4*)(As + crow * 32 + ccol) = av;
    if (tid < 192) *(uint4*)(Bs + crow * 32 + ccol) = bv;
    __syncthreads();
    s16x8 af = *(const s16x8*)(As + (wave * 16 + lrow) * 32 + lq * 8);
#pragma unroll
    for (int j = 0; j < 3; j++) {
      s16x8 bf8 = *(const s16x8*)(Bs + (j * 16 + lrow) * 32 + lq * 8);
      acc[j] = __builtin_amdgcn_mfma_f32_16x16x32_bf16(af, bf8, acc[j], 0, 0, 0);
    }
  }

  float ad = A_diag[lrow];
#pragma unroll
  for (int r = 0; r < 4; r++) {
    int row = r0 + wave * 16 + lq * 4 + r;
    float z  = acc[0][r];
    float sp = fmaxf(z, 0.0f) + log1pf(__expf(-fabsf(z)));  // softplus
    float ab = __expf(sp * ad);                              // A_bar in (0,1]
    float2 o;
    o.x = ab * TWO_LOG2E;
    o.y = acc[1][r] * TWO_LOG2E;
    *(float2*)(AB + (size_t)row * 32 + lrow * 2) = o;
    Ct[(size_t)row * 16 + lrow] = acc[2][r];
  }
}

// ------------------------------------------------------------------ K5 scan
// h_t = m*tanh(A_bar h + B) + (1-m) h. 128 chains (b,s), lane = chain.
// tanh via exp2: w pre-scaled by 2*log2e; tanh = 1 - 2/(exp2(w)+1).
// CH-step chunks, double-buffered in named register arrays (no dynamic
// indexing -> no scratch). ~32 independent loads in flight per chunk hide
// the ~200-cycle L2 latency that dominated R1 (201 cyc/step measured).
__global__ __launch_bounds__(64) void k_scan(
    const float* __restrict__ AB, const float* __restrict__ mask,
    const float* __restrict__ h0, float* __restrict__ hs,
    float* __restrict__ hfin) {
  const int lane = threadIdx.x;
  const int b = blockIdx.x * 4 + (lane >> 4);
  const int s = lane & 15;
  const size_t abase = ((size_t)b * 4096) * 32 + s * 2;
  const size_t hbase = ((size_t)b * 4096) * 16 + s;
  const float* pm = mask + (size_t)b * 4096;

  float h = h0[b * 16 + s];
  float2 bA0[CH], bA1[CH];
  float  bM0[CH], bM1[CH];

#pragma unroll
  for (int i = 0; i < CH; i++) {              // prefetch chunk 0
    bA0[i] = *(const float2*)(AB + abase + (size_t)i * 32);
    bM0[i] = pm[i];
  }

  for (int c = 0; c < 4096 / CH; c += 2) {
    { // prefetch chunk c+1 into buf1, compute chunk c from buf0
      int tn = (c + 1) * CH;
#pragma unroll
      for (int i = 0; i < CH; i++) {
        bA1[i] = *(const float2*)(AB + abase + (size_t)(tn + i) * 32);
        bM1[i] = pm[tn + i];
      }
      bool ones = true;
#pragma unroll
      for (int i = 0; i < CH; i++) ones = ones && (bM0[i] == 1.0f);
      size_t hb = hbase + (size_t)(c * CH) * 16;
      if (__all(ones)) {
#pragma unroll
        for (int i = 0; i < CH; i++) {
          float w  = fmaf(bA0[i].x, h, bA0[i].y);
          float e  = __builtin_amdgcn_exp2f(w);
          float rc = __builtin_amdgcn_rcpf(e + 1.0f);
          h = fmaf(-2.0f, rc, 1.0f);
          hs[hb + (size_t)i * 16] = h;
        }
      } else {
#pragma unroll
        for (int i = 0; i < CH; i++) {
          float w  = fmaf(bA0[i].x, h, bA0[i].y);
          float e  = __builtin_amdgcn_exp2f(w);
          float rc = __builtin_amdgcn_rcpf(e + 1.0f);
          float th = fmaf(-2.0f, rc, 1.0f);
          h = fmaf(bM0[i], th - h, h);
          hs[hb + (size_t)i * 16] = h;
        }
      }
    }
    { // prefetch chunk c+2 into buf0, compute chunk c+1 from buf1
      int tn = (c + 2) * CH;
      int tp = (tn < 4096) ? tn : 0;          // last prefetch is a dummy
#pragma unroll
      for (int i = 0; i < CH; i++) {
        bA0[i] = *(const float2*)(AB + abase + (size_t)(tp + i) * 32);
        bM0[i] = pm[tp + i];
      }
      bool ones = true;
#pragma unroll
      for (int i = 0; i < CH; i++) ones = ones && (bM1[i] == 1.0f);
      size_t hb = hbase + (size_t)((c + 1) * CH) * 16;
      if (__all(ones)) {
#pragma unroll
        for (int i = 0; i < CH; i++) {
          float w  = fmaf(bA1[i].x, h, bA1[i].y);
          float e  = __builtin_amdgcn_exp2f(w);
          float rc = __builtin_amdgcn_rcpf(e + 1.0f);
          h = fmaf(-2.0f, rc, 1.0f);
          hs[hb + (size_t)i * 16] = h;
        }
      } else {
#pragma unroll
        for (int i = 0; i < CH; i++) {
          float w  = fmaf(bA1[i].x, h, bA1[i].y);
          float e  = __builtin_amdgcn_exp2f(w);
          float rc = __builtin_amdgcn_rcpf(e + 1.0f);
          float th = fmaf(-2.0f, rc, 1.0f);
          h = fmaf(bM1[i], th - h, h);
          hs[hb + (size_t)i * 16] = h;
        }
      }
    }
  }
  hfin[b * 16 + s] = h;
}

// ---------------------------------------------------------------- K6 output
__global__ __launch_bounds__(256) void k_out(
    const float* __restrict__ Ct, const float* __restrict__ hs,
    const float* __restrict__ Wout, const float* __restrict__ Dd,
    const float* __restrict__ x, float* __restrict__ y) {
  __shared__ float sv[8][16];
  const int t = threadIdx.x;
  const size_t r0 = (size_t)blockIdx.x * 8;
  const int d0 = t * 4;

  float w[4][16];
#pragma unroll
  for (int i = 0; i < 4; i++)
#pragma unroll
    for (int s4 = 0; s4 < 4; s4++)
      *(float4*)&w[i][s4 * 4] = *(const float4*)(Wout + (size_t)(d0 + i) * 16 + s4 * 4);
  float4 D4 = *(const float4*)(Dd + d0);

  if (t < 128) {
    int rr = t >> 4, s = t & 15;
    size_t idx = (r0 + rr) * 16 + s;
    sv[rr][s] = Ct[idx] * hs[idx];
  }
  __syncthreads();

#pragma unroll
  for (int rr = 0; rr < 8; rr++) {
    size_t r = r0 + rr;
    float4 x4 = *(const float4*)(x + r * 1024 + d0);
    float4 o;
    o.x = D4.x * x4.x; o.y = D4.y * x4.y; o.z = D4.z * x4.z; o.w = D4.w * x4.w;
#pragma unroll
    for (int s = 0; s < 16; s++) {
      float svs = sv[rr][s];
      o.x = fmaf(w[0][s], svs, o.x);
      o.y = fmaf(w[1][s], svs, o.y);
      o.z = fmaf(w[2][s], svs, o.z);
      o.w = fmaf(w[3][s], svs, o.w);
    }
    *(float4*)(y + r * 1024 + d0) = o;
  }
}

// ---------------------------------------------------------------- launcher
extern "C" void kernel_launch(void* const* d_in, const int* in_sizes, int n_in,
                              void* d_out, int out_size, void* d_ws, size_t ws_size,
                              hipStream_t stream) {
  const float* x       = (const float*)d_in[0];
  const float* h0      = (const float*)d_in[1];
  const float* mask    = (const float*)d_in[2];
  const float* A_diag  = (const float*)d_in[3];
  const float* W_delta = (const float*)d_in[4];
  const float* W_B     = (const float*)d_in[5];
  const float* W_C     = (const float*)d_in[6];
  const float* W_out   = (const float*)d_in[7];
  const float* Dd      = (const float*)d_in[8];
  const float* W_gate  = (const float*)d_in[9];
  const float* b_gate  = (const float*)d_in[10];
  const float* ln_w    = (const float*)d_in[11];
  const float* ln_b    = (const float*)d_in[12];

  char* ws = (char*)d_ws;
  unsigned short* Xb   = (unsigned short*)(ws);               // 64 MB
  unsigned short* Gb   = (unsigned short*)(ws + 67108864);    // 64 MB (G, then xg in-place)
  unsigned short* Wgb  = (unsigned short*)(ws + 134217728);   // 2 MB
  unsigned short* Wcat = (unsigned short*)(ws + 136314880);   // 96 KB (pad 128K)
  float* ABb = (float*)(ws + 136445952);                      // 4 MB interleaved {A2,B2}
  float* Ctb = (float*)(ws + 140640256);                      // 2 MB
  float* hsb = (float*)(ws + 142737408);                      // 2 MB  (end ~138.1 MB)

  float* y    = (float*)d_out;
  float* hfin = y + 33554432;

  hipLaunchKernelGGL(k_convert, dim3(33840), dim3(256), 0, stream,
                     x, W_gate, W_delta, W_B, W_C, Xb, Wgb, Wcat);
  hipLaunchKernelGGL(k_gemm_gate, dim3(256, 8), dim3(256), 0, stream, Xb, Wgb, Gb);
  hipLaunchKernelGGL(k_lngate, dim3(32768), dim3(256), 0, stream,
                     Gb, x, b_gate, ln_w, ln_b, Gb);
  hipLaunchKernelGGL(k_proj, dim3(512), dim3(256), 0, stream,
                     Gb, Wcat, A_diag, ABb, Ctb);
  hipLaunchKernelGGL(k_scan, dim3(2), dim3(64), 0, stream,
                     ABb, mask, h0, hsb, hfin);
  hipLaunchKernelGGL(k_out, dim3(4096), dim3(256), 0, stream,
                     Ctb, hsb, W_out, Dd, x, y);
}

// Round 3
// 553.912 us; speedup vs baseline: 1.4164x; 1.2221x over previous
//
#include <hip/hip_runtime.h>
#include <hip/hip_bf16.h>
#include <cstdint>

// SimplifiedMambaSSM on MI355X (gfx950)
// B=8, T=4096, D_MODEL=1024, D_STATE=16. Rows M = B*T = 32768.
//
// Pipeline:
//  K1 convert : x, W_gate, [W_delta;W_B;W_C] -> bf16 workspace copies
//  K2 gemm    : G = Xb @ Wgb^T   (32768x1024x1024 bf16 MFMA, 128x128 tiles)
//  K3 lngate  : xg = sigmoid(LN(G + b_gate)) * x   (in-place over G, bf16)
//  K4 proj    : [delta|B|C] = xg @ Wcat^T (skinny MFMA); epilogue folds
//               softplus/exp(A_diag)/2*log2e AND the r-domain substitution:
//               writes {u = A2+B2, v = -2*A2} pairs so the scan chain is
//               fma -> exp2 -> add -> rcp (4 dependent ops).
//  K5 scan    : wave-specialized. Waves 1-7 stage 128-step (u,v) chunks into
//               double-buffered LDS and flush h-history; wave 0 lanes 0-15
//               run the serial recurrence from LDS. Barrier-enforced
//               prefetch distance (R2: compiler sank register prefetch,
//               VGPR=36, 133 cyc/step).
//  K6 out     : y = (C .* h) @ W_out^T + D .* x
//
#define M_TOK   32768
#define LNEPS   1e-5f
#define TWO_LOG2E 2.8853900817779268f   // 2/ln(2)

typedef float  f32x4 __attribute__((ext_vector_type(4)));
typedef short  s16x8 __attribute__((ext_vector_type(8)));

__device__ __forceinline__ unsigned short f2b(float v) {
  return __builtin_bit_cast(unsigned short, __float2bfloat16(v));
}
__device__ __forceinline__ float b2f(unsigned short u) {
  return __bfloat162float(__builtin_bit_cast(__hip_bfloat16, u));
}

// async global->LDS, 16B per lane. LDS dest is wave-uniform base + lane*16.
__device__ __forceinline__ void async_cp16(const void* g, void* l) {
  using gp = const __attribute__((address_space(1))) char*;
  using lp = __attribute__((address_space(3))) char*;
  __builtin_amdgcn_global_load_lds((gp)(uint64_t)g,
                                   (lp)(uint32_t)(uint64_t)l, 16, 0, 0);
}

// ---------------------------------------------------------------- K1 convert
__global__ __launch_bounds__(256) void k_convert(
    const float* __restrict__ x, const float* __restrict__ wg,
    const float* __restrict__ wd, const float* __restrict__ wb,
    const float* __restrict__ wc,
    unsigned short* __restrict__ Xb, unsigned short* __restrict__ Wgb,
    unsigned short* __restrict__ Wcat) {
  int i = blockIdx.x * 256 + threadIdx.x;   // one float4 per thread
  const float* src;
  unsigned short* dst;
  if (i < 8388608) {                  // x: 33554432 floats
    src = x + (size_t)i * 4; dst = Xb + (size_t)i * 4;
  } else if (i < 8650752) {           // W_gate: 1048576 floats
    int j = i - 8388608;
    src = wg + (size_t)j * 4; dst = Wgb + (size_t)j * 4;
  } else {                            // Wcat = [W_delta; W_B; W_C], 49152 floats
    int j = i - 8650752;
    int e = j * 4;
    if (e < 16384)       src = wd + e;
    else if (e < 32768)  src = wb + (e - 16384);
    else                 src = wc + (e - 32768);
    dst = Wcat + e;
  }
  float4 v = *(const float4*)src;
  ushort4 o;
  o.x = f2b(v.x); o.y = f2b(v.y); o.z = f2b(v.z); o.w = f2b(v.w);
  *(ushort4*)dst = o;
}

// ------------------------------------------------------------- K2 gate GEMM
// G[m][n] = sum_k Xb[m][k] * Wgb[n][k]   (NT, both K-contiguous)
// 128x128 block tile, 4 waves in 2x2, each wave 64x64 = 4x4 MFMA 16x16x32.
__global__ __launch_bounds__(256, 2) void k_gemm_gate(
    const unsigned short* __restrict__ A,   // [32768][1024] bf16
    const unsigned short* __restrict__ Bm,  // [1024][1024] bf16 (W_gate rows)
    unsigned short* __restrict__ C) {       // [32768][1024] bf16
  __shared__ unsigned short As[128 * 32];   // 8 KB
  __shared__ unsigned short Bs[128 * 32];   // 8 KB
  const int tid  = threadIdx.x;
  const int wave = tid >> 6, lane = tid & 63;
  const int wr = wave >> 1, wc = wave & 1;
  const int lrow = lane & 15, lq = lane >> 4;
  const int m0 = blockIdx.x * 128;
  const int n0 = blockIdx.y * 128;
  const int crow  = tid >> 2;               // staging chunk row (rep 0)
  const int ccol  = (tid & 3) * 8;          // staging chunk col (elems)

  f32x4 acc[4][4];
#pragma unroll
  for (int i = 0; i < 4; i++)
#pragma unroll
    for (int j = 0; j < 4; j++) acc[i][j] = (f32x4){0.f, 0.f, 0.f, 0.f};

  for (int k0 = 0; k0 < 1024; k0 += 32) {
    async_cp16(A + (size_t)(m0 + crow) * 1024 + k0 + ccol,
               (void*)(As + (wave * 64) * 8));
    async_cp16(A + (size_t)(m0 + crow + 64) * 1024 + k0 + ccol,
               (void*)(As + (256 + wave * 64) * 8));
    async_cp16(Bm + (size_t)(n0 + crow) * 1024 + k0 + ccol,
               (void*)(Bs + (wave * 64) * 8));
    async_cp16(Bm + (size_t)(n0 + crow + 64) * 1024 + k0 + ccol,
               (void*)(Bs + (256 + wave * 64) * 8));
    __syncthreads();   // drains vmcnt (global_load_lds) before LDS reads

    s16x8 af[4], bfr[4];
#pragma unroll
    for (int i = 0; i < 4; i++)
      af[i] = *(const s16x8*)(As + (wr * 64 + i * 16 + lrow) * 32 + lq * 8);
#pragma unroll
    for (int j = 0; j < 4; j++)
      bfr[j] = *(const s16x8*)(Bs + (wc * 64 + j * 16 + lrow) * 32 + lq * 8);
#pragma unroll
    for (int i = 0; i < 4; i++)
#pragma unroll
      for (int j = 0; j < 4; j++)
        acc[i][j] = __builtin_amdgcn_mfma_f32_16x16x32_bf16(
            af[i], bfr[j], acc[i][j], 0, 0, 0);
    __syncthreads();
  }

  // C/D layout: col = lane&15, row = (lane>>4)*4 + reg
#pragma unroll
  for (int i = 0; i < 4; i++)
#pragma unroll
    for (int j = 0; j < 4; j++)
#pragma unroll
      for (int r = 0; r < 4; r++) {
        int row = m0 + wr * 64 + i * 16 + lq * 4 + r;
        int col = n0 + wc * 64 + j * 16 + lrow;
        C[(size_t)row * 1024 + col] = f2b(acc[i][j][r]);
      }
}

// -------------------------------------------------------------- K3 LN+gate
__global__ __launch_bounds__(256) void k_lngate(
    const unsigned short* Gin, const float* __restrict__ x,
    const float* __restrict__ bg, const float* __restrict__ lnw,
    const float* __restrict__ lnb, unsigned short* XG) {
  __shared__ float red[8];
  const int t = threadIdx.x;
  const size_t r = blockIdx.x;
  const int e = t * 4;

  ushort4 g4 = *(const ushort4*)(Gin + r * 1024 + e);
  float4 bg4 = *(const float4*)(bg + e);
  float v0 = b2f(g4.x) + bg4.x;
  float v1 = b2f(g4.y) + bg4.y;
  float v2 = b2f(g4.z) + bg4.z;
  float v3 = b2f(g4.w) + bg4.w;

  float s  = v0 + v1 + v2 + v3;
  float ss = v0 * v0 + v1 * v1 + v2 * v2 + v3 * v3;
#pragma unroll
  for (int off = 32; off >= 1; off >>= 1) {
    s  += __shfl_xor(s, off, 64);
    ss += __shfl_xor(ss, off, 64);
  }
  if ((t & 63) == 0) { red[t >> 6] = s; red[4 + (t >> 6)] = ss; }
  __syncthreads();
  float tot = red[0] + red[1] + red[2] + red[3];
  float tss = red[4] + red[5] + red[6] + red[7];
  float mu  = tot * (1.0f / 1024.0f);
  float var = tss * (1.0f / 1024.0f) - mu * mu;
  float rs  = rsqrtf(var + LNEPS);

  float4 xv = *(const float4*)(x + r * 1024 + e);
  float4 w4 = *(const float4*)(lnw + e);
  float4 b4 = *(const float4*)(lnb + e);
  float u0 = (v0 - mu) * rs * w4.x + b4.x;
  float u1 = (v1 - mu) * rs * w4.y + b4.y;
  float u2 = (v2 - mu) * rs * w4.z + b4.z;
  float u3 = (v3 - mu) * rs * w4.w + b4.w;
  float g0 = 1.0f / (1.0f + __expf(-u0));
  float g1 = 1.0f / (1.0f + __expf(-u1));
  float g2 = 1.0f / (1.0f + __expf(-u2));
  float g3 = 1.0f / (1.0f + __expf(-u3));
  ushort4 o;
  o.x = f2b(g0 * xv.x); o.y = f2b(g1 * xv.y);
  o.z = f2b(g2 * xv.z); o.w = f2b(g3 * xv.w);
  *(ushort4*)(XG + r * 1024 + e) = o;
}

// ------------------------------------------------------------ K4 projection
// Epilogue writes UV[row*32 + s*2] = {u = A2+B2, v = -2*A2} where
// A2 = exp(softplus(delta)*A_diag)*2log2e, B2 = B*2log2e. Ct written flat.
__global__ __launch_bounds__(256) void k_proj(
    const unsigned short* __restrict__ XG, const unsigned short* __restrict__ Wcat,
    const float* __restrict__ A_diag,
    float* __restrict__ UV, float* __restrict__ Ct) {
  __shared__ unsigned short As[64 * 32];   // 4 KB
  __shared__ unsigned short Bs[48 * 32];   // 3 KB
  const int tid  = threadIdx.x;
  const int wave = tid >> 6, lane = tid & 63;
  const int lrow = lane & 15, lq = lane >> 4;
  const int r0 = blockIdx.x * 64;
  const int crow = tid >> 2, ccol = (tid & 3) * 8;

  f32x4 acc[3];
#pragma unroll
  for (int j = 0; j < 3; j++) acc[j] = (f32x4){0.f, 0.f, 0.f, 0.f};

  for (int k0 = 0; k0 < 1024; k0 += 32) {
    uint4 av = *(const uint4*)(XG + (size_t)(r0 + crow) * 1024 + k0 + ccol);
    uint4 bv;
    if (tid < 192) bv = *(const uint4*)(Wcat + (size_t)crow * 1024 + k0 + ccol);
    __syncthreads();                       // prev iter done reading LDS
    *(uint4*)(As + crow * 32 + ccol) = av;
    if (tid < 192) *(uint4*)(Bs + crow * 32 + ccol) = bv;
    __syncthreads();
    s16x8 af = *(const s16x8*)(As + (wave * 16 + lrow) * 32 + lq * 8);
#pragma unroll
    for (int j = 0; j < 3; j++) {
      s16x8 bf8 = *(const s16x8*)(Bs + (j * 16 + lrow) * 32 + lq * 8);
      acc[j] = __builtin_amdgcn_mfma_f32_16x16x32_bf16(af, bf8, acc[j], 0, 0, 0);
    }
  }

  float ad = A_diag[lrow];
#pragma unroll
  for (int r = 0; r < 4; r++) {
    int row = r0 + wave * 16 + lq * 4 + r;
    float z  = acc[0][r];
    float sp = fmaxf(z, 0.0f) + log1pf(__expf(-fabsf(z)));  // softplus
    float A2 = __expf(sp * ad) * TWO_LOG2E;                  // A_bar scaled
    float B2 = acc[1][r] * TWO_LOG2E;
    float2 o;
    o.x = A2 + B2;          // u
    o.y = -2.0f * A2;       // v
    *(float2*)(UV + (size_t)row * 32 + lrow * 2) = o;
    Ct[(size_t)row * 16 + lrow] = acc[2][r];
  }
}

// ------------------------------------------------------------------ K5 scan
// Wave-specialized. One block per batch b (8 blocks x 512 threads).
// Waves 1-7: stage 128-step (u,v) chunks (16 KB) into double-buffered LDS,
// flush 8 KB h-history chunks to global. Wave 0 lanes 0-15: serial
// recurrence. Fast path (mask==1, checked per chunk via ballot) carries
// r with chain fma -> exp2 -> add -> rcp; h = 1-2r off-chain.
// Slow path carries h; invariant r = 0.5*(1-h) restored at chunk ends.
#define TC 128                // steps per chunk
#define NCH (4096 / TC)       // 32 chunks

__device__ __forceinline__ void load16(float2 (&P)[16], const float* uvb,
                                       int j, int lane) {
#pragma unroll
  for (int i = 0; i < 16; ++i)
    P[i] = *(const float2*)(uvb + ((j * 16 + i) * 16 + lane) * 2);
}
__device__ __forceinline__ void fast16(float2 (&P)[16], float& r, float& h,
                                       float* hhb, int j, int lane) {
#pragma unroll
  for (int i = 0; i < 16; ++i) {
    float w = fmaf(P[i].y, r, P[i].x);
    float e = __builtin_amdgcn_exp2f(w);
    r = __builtin_amdgcn_rcpf(e + 1.0f);
    h = fmaf(-2.0f, r, 1.0f);
    hhb[(j * 16 + i) * 16 + lane] = h;
  }
}
__device__ __forceinline__ void slow16(float2 (&P)[16], float& h,
                                       const float* mb, float* hhb,
                                       int j, int lane) {
#pragma unroll
  for (int i = 0; i < 16; ++i) {
    float v  = P[i].y, u = P[i].x;
    float A2 = -0.5f * v;
    float B2 = fmaf(0.5f, v, u);
    float w  = fmaf(A2, h, B2);
    float e  = __builtin_amdgcn_exp2f(w);
    float rr = __builtin_amdgcn_rcpf(e + 1.0f);
    float th = fmaf(-2.0f, rr, 1.0f);
    float m  = mb[j * 16 + i];
    h = fmaf(m, th - h, h);
    hhb[(j * 16 + i) * 16 + lane] = h;
  }
}

__global__ __launch_bounds__(512) void k_scan(
    const float* __restrict__ UV, const float* __restrict__ mask,
    const float* __restrict__ h0, float* __restrict__ hs,
    float* __restrict__ hfin) {
  __shared__ float uvL[2][TC * 32];    // 2 x 16 KB
  __shared__ float hhL[2][TC * 16];    // 2 x 8 KB
  __shared__ float mskL[2][TC];        // 2 x 512 B

  const int tid = threadIdx.x;
  const int b   = blockIdx.x;
  const float* pm = mask + (size_t)b * 4096;
  const size_t uvbase = (size_t)b * 4096 * 32;   // floats
  const size_t hsbase = (size_t)b * 4096 * 16;   // floats

  float h = 0.f, r = 0.f;
  if (tid < 16) {
    h = h0[b * 16 + tid];
    r = 0.5f - 0.5f * h;        // invariant r = (1-h)/2
  }

  // ---- priming: load chunk 0 (UV + mask)
  if (tid >= 64) {
    int pt = tid - 64;                          // 0..447
    const uint4* src = (const uint4*)(UV + uvbase);
    for (int i = pt; i < TC * 8; i += 448) ((uint4*)uvL[0])[i] = src[i];
    if (tid < 128) {
      int l = tid - 64;
      mskL[0][l]      = pm[l];
      mskL[0][l + 64] = pm[l + 64];
    }
  }
  __syncthreads();

  for (int c = 0; c < NCH; ++c) {
    const int p = c & 1;
    if (tid < 64) {
      // ---------------- consumer wave
      const int lane = tid;
      float mv0 = mskL[p][2 * lane], mv1 = mskL[p][2 * lane + 1];
      bool on = (mv0 == 1.0f) && (mv1 == 1.0f);
      bool allones = (__ballot(on) == 0xFFFFFFFFFFFFFFFFull);
      if (lane < 16) {
        const float* uvb = uvL[p];
        float* hhb = hhL[p];
        float2 Pa[16], Pb[16];
        load16(Pa, uvb, 0, lane);
        if (allones) {
#pragma unroll
          for (int j = 0; j < 8; j += 2) {
            load16(Pb, uvb, j + 1, lane);
            fast16(Pa, r, h, hhb, j, lane);
            if (j + 2 < 8) load16(Pa, uvb, j + 2, lane);
            fast16(Pb, r, h, hhb, j + 1, lane);
          }
          // h already = 1 - 2r
        } else {
#pragma unroll
          for (int j = 0; j < 8; j += 2) {
            load16(Pb, uvb, j + 1, lane);
            slow16(Pa, h, mskL[p], hhb, j, lane);
            if (j + 2 < 8) load16(Pa, uvb, j + 2, lane);
            slow16(Pb, h, mskL[p], hhb, j + 1, lane);
          }
          r = 0.5f - 0.5f * h;
        }
      }
    } else {
      // ---------------- producer waves 1..7
      int pt = tid - 64;                        // 0..447
      if (c + 1 < NCH) {
        const uint4* src =
            (const uint4*)(UV + uvbase + (size_t)(c + 1) * TC * 32);
        uint4* dst = (uint4*)uvL[(c + 1) & 1];
        for (int i = pt; i < TC * 8; i += 448) dst[i] = src[i];
        if (tid < 128) {
          int l = tid - 64;
          mskL[(c + 1) & 1][l]      = pm[(c + 1) * TC + l];
          mskL[(c + 1) & 1][l + 64] = pm[(c + 1) * TC + l + 64];
        }
      }
      if (c > 0) {
        const uint4* s2 = (const uint4*)hhL[(c - 1) & 1];
        uint4* d2 = (uint4*)(hs + hsbase + (size_t)(c - 1) * TC * 16);
        for (int i = pt; i < TC * 4; i += 448) d2[i] = s2[i];
      }
    }
    __syncthreads();
  }

  // ---- epilogue: store last chunk's h-history (parity (NCH-1)&1 = 1)
  {
    const uint4* s2 = (const uint4*)hhL[(NCH - 1) & 1];
    uint4* d2 = (uint4*)(hs + hsbase + (size_t)(NCH - 1) * TC * 16);
    if (tid < TC * 4) d2[tid] = s2[tid];
  }
  if (tid < 16) hfin[b * 16 + tid] = h;
}

// ---------------------------------------------------------------- K6 output
__global__ __launch_bounds__(256) void k_out(
    const float* __restrict__ Ct, const float* __restrict__ hs,
    const float* __restrict__ Wout, const float* __restrict__ Dd,
    const float* __restrict__ x, float* __restrict__ y) {
  __shared__ float sv[8][16];
  const int t = threadIdx.x;
  const size_t r0 = (size_t)blockIdx.x * 8;
  const int d0 = t * 4;

  float w[4][16];
#pragma unroll
  for (int i = 0; i < 4; i++)
#pragma unroll
    for (int s4 = 0; s4 < 4; s4++)
      *(float4*)&w[i][s4 * 4] = *(const float4*)(Wout + (size_t)(d0 + i) * 16 + s4 * 4);
  float4 D4 = *(const float4*)(Dd + d0);

  if (t < 128) {
    int rr = t >> 4, s = t & 15;
    size_t idx = (r0 + rr) * 16 + s;
    sv[rr][s] = Ct[idx] * hs[idx];
  }
  __syncthreads();

#pragma unroll
  for (int rr = 0; rr < 8; rr++) {
    size_t r = r0 + rr;
    float4 x4 = *(const float4*)(x + r * 1024 + d0);
    float4 o;
    o.x = D4.x * x4.x; o.y = D4.y * x4.y; o.z = D4.z * x4.z; o.w = D4.w * x4.w;
#pragma unroll
    for (int s = 0; s < 16; s++) {
      float svs = sv[rr][s];
      o.x = fmaf(w[0][s], svs, o.x);
      o.y = fmaf(w[1][s], svs, o.y);
      o.z = fmaf(w[2][s], svs, o.z);
      o.w = fmaf(w[3][s], svs, o.w);
    }
    *(float4*)(y + r * 1024 + d0) = o;
  }
}

// ---------------------------------------------------------------- launcher
extern "C" void kernel_launch(void* const* d_in, const int* in_sizes, int n_in,
                              void* d_out, int out_size, void* d_ws, size_t ws_size,
                              hipStream_t stream) {
  const float* x       = (const float*)d_in[0];
  const float* h0      = (const float*)d_in[1];
  const float* mask    = (const float*)d_in[2];
  const float* A_diag  = (const float*)d_in[3];
  const float* W_delta = (const float*)d_in[4];
  const float* W_B     = (const float*)d_in[5];
  const float* W_C     = (const float*)d_in[6];
  const float* W_out   = (const float*)d_in[7];
  const float* Dd      = (const float*)d_in[8];
  const float* W_gate  = (const float*)d_in[9];
  const float* b_gate  = (const float*)d_in[10];
  const float* ln_w    = (const float*)d_in[11];
  const float* ln_b    = (const float*)d_in[12];

  char* ws = (char*)d_ws;
  unsigned short* Xb   = (unsigned short*)(ws);               // 64 MB
  unsigned short* Gb   = (unsigned short*)(ws + 67108864);    // 64 MB (G, then xg in-place)
  unsigned short* Wgb  = (unsigned short*)(ws + 134217728);   // 2 MB
  unsigned short* Wcat = (unsigned short*)(ws + 136314880);   // 96 KB (pad 128K)
  float* UVb = (float*)(ws + 136445952);                      // 4 MB interleaved {u,v}
  float* Ctb = (float*)(ws + 140640256);                      // 2 MB
  float* hsb = (float*)(ws + 142737408);                      // 2 MB  (end ~138.1 MB)

  float* y    = (float*)d_out;
  float* hfin = y + 33554432;

  hipLaunchKernelGGL(k_convert, dim3(33840), dim3(256), 0, stream,
                     x, W_gate, W_delta, W_B, W_C, Xb, Wgb, Wcat);
  hipLaunchKernelGGL(k_gemm_gate, dim3(256, 8), dim3(256), 0, stream, Xb, Wgb, Gb);
  hipLaunchKernelGGL(k_lngate, dim3(32768), dim3(256), 0, stream,
                     Gb, x, b_gate, ln_w, ln_b, Gb);
  hipLaunchKernelGGL(k_proj, dim3(512), dim3(256), 0, stream,
                     Gb, Wcat, A_diag, UVb, Ctb);
  hipLaunchKernelGGL(k_scan, dim3(8), dim3(512), 0, stream,
                     UVb, mask, h0, hsb, hfin);
  hipLaunchKernelGGL(k_out, dim3(4096), dim3(256), 0, stream,
                     Ctb, hsb, W_out, Dd, x, y);
}